// Round 4
// baseline (436.984 us; speedup 1.0000x reference)
//
#include <hip/hip_runtime.h>

typedef short short8 __attribute__((ext_vector_type(8)));
typedef float f32x4 __attribute__((ext_vector_type(4)));
typedef unsigned short ushort8_t __attribute__((ext_vector_type(8)));

#define O_CH 128
#define I_CH 128
#define HW 112
#define PLANE (HW * HW)      // 12544
#define NCOL 114             // 112 cols + 2 halo
#define CH 64                // channels per half; col stride = 128 B

__device__ __forceinline__ unsigned short f2bf(float f) {
  union { float f; unsigned u; } v; v.f = f;
  unsigned r = v.u + 0x7FFFu + ((v.u >> 16) & 1u);   // RNE
  return (unsigned short)(r >> 16);
}
__device__ __forceinline__ unsigned pk2bf(float a, float b) {
  return (unsigned)f2bf(a) | ((unsigned)f2bf(b) << 16);
}

__global__ void wsynth_kernel(const float* __restrict__ core,
                              const float* __restrict__ periph,
                              const float* __restrict__ thr,
                              const float* __restrict__ scale,
                              unsigned short* __restrict__ Wb) {
  int idx = blockIdx.x * blockDim.x + threadIdx.x;   // o*128 + i
  if (idx >= O_CH * I_CH) return;
  int o = idx >> 7;
  float c = core[idx];
  float s = scale[0];
  float g = 1.0f / (1.0f + __expf(-s * (fabsf(c) - thr[o])));
#pragma unroll
  for (int tap = 0; tap < 9; ++tap) {
    float p  = (tap == 4) ? 1.0f : periph[tap < 4 ? tap : tap - 1];
    float gg = (tap == 4) ? 1.0f : g;
    Wb[tap * (O_CH * I_CH) + idx] = f2bf(c * p * gg);   // layout [tap][o][i]
  }
}

__global__ __launch_bounds__(256, 3)
void conv_kernel(const float* __restrict__ X,
                 const unsigned short* __restrict__ Wb,
                 float* __restrict__ Out) {
  // [row 0..2][col 0..113][ch 0..63] bf16, swizzled: byte ^= (col&7)<<4
  __shared__ unsigned short Xs[3 * NCOL * CH];   // 43,776 B -> 3 WGs/CU
  char* lds = (char*)Xs;

  // identity mapping (XCD swizzle measured WORSE in R2: FETCH 322->393 MB)
  const int bid = blockIdx.x;
  const int b = bid / HW;
  const int y = bid - b * HW;

  const int t   = threadIdx.x;
  const int wv  = t >> 6;           // wave 0..3 -> o quarter
  const int l   = t & 63;
  const int ln  = l & 15;           // MFMA frag lane
  const int lk4 = l >> 4;           // k-slice 0..3

  // staging coords
  const int col  = t & 127;         // staged col (input col + 1)
  const int i2   = t >> 7;          // 0..1 -> 32-ch block
  const int icol = col - 1;
  const bool cok = (col < NCOL);

  f32x4 acc[2][7];
#pragma unroll
  for (int mr = 0; mr < 2; ++mr)
#pragma unroll
    for (int nf = 0; nf < 7; ++nf)
      acc[mr][nf] = (f32x4)0.0f;

  // per-thread invariant LDS read base (bytes): ln*128 + lk4*16
  const int rdbase = ln * 128 + lk4 * 16;

  for (int h = 0; h < 2; ++h) {
    if (h) __syncthreads();   // finish compute on previous half before overwrite

    // prefetch tap 0 A-fragments (no LDS dependency; completes across barrier)
    const unsigned short* wh = Wb + (wv * 32 + ln) * I_CH + lk4 * 8 + h * CH;
    short8 c00 = *reinterpret_cast<const short8*>(wh);
    short8 c10 = *reinterpret_cast<const short8*>(wh + 16 * I_CH);
    short8 c01 = *reinterpret_cast<const short8*>(wh + 32);
    short8 c11 = *reinterpret_cast<const short8*>(wh + 32 + 16 * I_CH);

    // ---- stage rows y-1..y+1, channels [h*64, h*64+64) as bf16, swizzled ----
#pragma unroll
    for (int r = 0; r < 3; ++r) {
      const int row = y + r - 1;
      const bool vok = (row >= 0) && (row < HW) && (icol >= 0) && (icol < HW);
      const float* sp0 = X + ((size_t)(b * I_CH + h * CH + i2 * 32) * HW + row) * HW + icol;
#pragma unroll
      for (int q8 = 0; q8 < 4; ++q8) {       // 8 channels per iteration
        const float* sp = sp0 + (size_t)q8 * 8 * PLANE;
        float v0 = 0.f, v1 = 0.f, v2 = 0.f, v3 = 0.f;
        float v4 = 0.f, v5 = 0.f, v6 = 0.f, v7 = 0.f;
        if (vok) {
          v0 = sp[0 * PLANE]; v1 = sp[1 * PLANE];
          v2 = sp[2 * PLANE]; v3 = sp[3 * PLANE];
          v4 = sp[4 * PLANE]; v5 = sp[5 * PLANE];
          v6 = sp[6 * PLANE]; v7 = sp[7 * PLANE];
        }
        if (cok) {
          union { ushort8_t s; unsigned u[4]; } pk;
          pk.u[0] = pk2bf(v0, v1);
          pk.u[1] = pk2bf(v2, v3);
          pk.u[2] = pk2bf(v4, v5);
          pk.u[3] = pk2bf(v6, v7);
          const int byteoff = (((r * NCOL + col) * CH + i2 * 32 + q8 * 8) * 2)
                              ^ ((col & 7) << 4);
          *reinterpret_cast<ushort8_t*>(lds + byteoff) = pk.s;
        }
      }
    }
    __syncthreads();

    // ---- compute: 9 taps, A pipelined one tap ahead ----
#pragma unroll
    for (int tap = 0; tap < 9; ++tap) {
      short8 n00, n10, n01, n11;
      if (tap < 8) {
        const unsigned short* wn = wh + (tap + 1) * (O_CH * I_CH);
        n00 = *reinterpret_cast<const short8*>(wn);
        n10 = *reinterpret_cast<const short8*>(wn + 16 * I_CH);
        n01 = *reinterpret_cast<const short8*>(wn + 32);
        n11 = *reinterpret_cast<const short8*>(wn + 32 + 16 * I_CH);
      }
      const int r  = tap / 3;
      const int dx = tap % 3;
      const int xorv = ((dx + ln) & 7) << 4;
      const int taddr = rdbase + (r * NCOL + dx) * 128;
#pragma unroll
      for (int ci = 0; ci < 2; ++ci) {
        const short8 a0 = ci ? c01 : c00;
        const short8 a1 = ci ? c11 : c10;
#pragma unroll
        for (int nf = 0; nf < 7; ++nf) {
          short8 bb = *reinterpret_cast<const short8*>(
              lds + ((taddr + ci * 64 + nf * 16 * 128) ^ xorv));
          acc[0][nf] = __builtin_amdgcn_mfma_f32_16x16x32_bf16(a0, bb, acc[0][nf], 0, 0, 0);
          acc[1][nf] = __builtin_amdgcn_mfma_f32_16x16x32_bf16(a1, bb, acc[1][nf], 0, 0, 0);
        }
      }
      if (tap < 8) { c00 = n00; c10 = n10; c01 = n01; c11 = n11; }
    }
  }

  // ---- epilogue: C/D map col=lane&15, row=(lane>>4)*4+j; plain stores ----
  const int obase = wv * 32 + lk4 * 4;
  float* outp = Out + (size_t)b * O_CH * PLANE + (size_t)y * HW;
#pragma unroll
  for (int mr = 0; mr < 2; ++mr) {
#pragma unroll
    for (int j = 0; j < 4; ++j) {
      const int o = obase + mr * 16 + j;
      float* po = outp + (size_t)o * PLANE;
#pragma unroll
      for (int nf = 0; nf < 7; ++nf) {
        po[nf * 16 + ln] = acc[mr][nf][j];
      }
    }
  }
}

extern "C" void kernel_launch(void* const* d_in, const int* in_sizes, int n_in,
                              void* d_out, int out_size, void* d_ws, size_t ws_size,
                              hipStream_t stream) {
  const float* x      = (const float*)d_in[0];
  const float* core   = (const float*)d_in[1];
  const float* periph = (const float*)d_in[2];
  const float* thr    = (const float*)d_in[3];
  const float* scale  = (const float*)d_in[4];
  unsigned short* Wb  = (unsigned short*)d_ws;   // 9*128*128*2 = 294,912 B

  wsynth_kernel<<<(O_CH * I_CH + 255) / 256, 256, 0, stream>>>(core, periph, thr, scale, Wb);

  const int grid = 32 * HW;   // one WG per (batch, output row) = 3584
  conv_kernel<<<grid, 256, 0, stream>>>(x, Wb, (float*)d_out);
}

// Round 5
// 217.647 us; speedup vs baseline: 2.0078x; 2.0078x over previous
//
#include <hip/hip_runtime.h>

typedef short short8 __attribute__((ext_vector_type(8)));
typedef float f32x4 __attribute__((ext_vector_type(4)));
typedef unsigned short ushort8_t __attribute__((ext_vector_type(8)));

#define O_CH 128
#define I_CH 128
#define HW 112
#define PLANE (HW * HW)        // 12544
#define NCOL 114               // 112 cols + 2 halo
#define BUFB (3 * NCOL * 64)   // bytes per LDS buffer: 3 rows * 114 cols * 32ch * 2B = 21888

__device__ __forceinline__ unsigned short f2bf(float f) {
  union { float f; unsigned u; } v; v.f = f;
  unsigned r = v.u + 0x7FFFu + ((v.u >> 16) & 1u);   // RNE
  return (unsigned short)(r >> 16);
}
__device__ __forceinline__ unsigned pk2bf(float a, float b) {
  return (unsigned)f2bf(a) | ((unsigned)f2bf(b) << 16);
}

__global__ void wsynth_kernel(const float* __restrict__ core,
                              const float* __restrict__ periph,
                              const float* __restrict__ thr,
                              const float* __restrict__ scale,
                              unsigned short* __restrict__ Wb) {
  int idx = blockIdx.x * blockDim.x + threadIdx.x;   // o*128 + i
  if (idx >= O_CH * I_CH) return;
  int o = idx >> 7;
  float c = core[idx];
  float s = scale[0];
  float g = 1.0f / (1.0f + __expf(-s * (fabsf(c) - thr[o])));
#pragma unroll
  for (int tap = 0; tap < 9; ++tap) {
    float p  = (tap == 4) ? 1.0f : periph[tap < 4 ? tap : tap - 1];
    float gg = (tap == 4) ? 1.0f : g;
    Wb[tap * (O_CH * I_CH) + idx] = f2bf(c * p * gg);   // layout [tap][o][i]
  }
}

__global__ __launch_bounds__(256, 2)
void conv_kernel(const float* __restrict__ X,
                 const unsigned short* __restrict__ Wb,
                 float* __restrict__ Out) {
  // 2 buffers x [row 0..2][col 0..113][32 ch] bf16; col-row = 64 B = 4 slots of 16 B,
  // slot swizzled: slot' = kslice ^ (c&3) ^ (((c>>2)&1)<<1)  (within-row, bijective)
  __shared__ unsigned short Xs[2 * 3 * NCOL * 32];   // 43,776 B -> 3 WGs/CU
  char* lds = (char*)Xs;

  const int bid = blockIdx.x;          // identity mapping (as R0)
  const int b = bid / HW;
  const int y = bid - b * HW;

  const int t   = threadIdx.x;
  const int wv  = t >> 6;              // wave 0..3 -> o quarter
  const int l   = t & 63;
  const int ln  = l & 15;              // MFMA frag lane
  const int lk4 = l >> 4;              // k-slice 0..3

  // staging coords
  const int c    = t & 127;            // staged col (input col + 1)
  const int chb  = (t >> 7) * 16;      // local channel base: 0 or 16
  const int icol = c - 1;
  const bool cok = (c < NCOL);
  const int wxor = (c & 3) ^ (((c >> 2) & 1) << 1);

  f32x4 acc[2][7];
#pragma unroll
  for (int mr = 0; mr < 2; ++mr)
#pragma unroll
    for (int nf = 0; nf < 7; ++nf)
      acc[mr][nf] = (f32x4)0.0f;

  // ---- prologue: stage chunk 0 (channels 0..31) into buffer 0 ----
#pragma unroll
  for (int sub = 0; sub < 3; ++sub) {
    const int row = y + sub - 1;
    const bool doL = (row >= 0) && (row < HW) && (icol >= 0) && (icol < HW);
    const float* sp = X + ((size_t)(b * I_CH + chb) * HW + row) * HW + icol;
    float v[16];
#pragma unroll
    for (int j = 0; j < 16; ++j) v[j] = 0.0f;
    if (doL) {
#pragma unroll
      for (int j = 0; j < 16; ++j) v[j] = sp[j * PLANE];
    }
    if (cok) {
      const int base = (sub * NCOL + c) * 64;
#pragma unroll
      for (int q = 0; q < 2; ++q) {
        union { ushort8_t s; unsigned u[4]; } pk;
        pk.u[0] = pk2bf(v[q * 8 + 0], v[q * 8 + 1]);
        pk.u[1] = pk2bf(v[q * 8 + 2], v[q * 8 + 3]);
        pk.u[2] = pk2bf(v[q * 8 + 4], v[q * 8 + 5]);
        pk.u[3] = pk2bf(v[q * 8 + 6], v[q * 8 + 7]);
        const int slot = ((chb >> 3) + q) ^ wxor;
        *reinterpret_cast<ushort8_t*>(lds + base + slot * 16) = pk.s;
      }
    }
  }
  __syncthreads();

  // ---- main loop: 4 chunks of 32 channels, double-buffered ----
#pragma unroll
  for (int k = 0; k < 4; ++k) {
    char* rbuf = lds + (k & 1) * BUFB;
    char* wbuf = lds + ((k & 1) ^ 1) * BUFB;
#pragma unroll
    for (int sub = 0; sub < 3; ++sub) {
      // (a) issue next chunk's global loads for this row
      float v[16];
      const int row = y + sub - 1;
      const bool doL = (k < 3) && (row >= 0) && (row < HW) && (icol >= 0) && (icol < HW);
      const float* sp = X + ((size_t)(b * I_CH + (k < 3 ? (k + 1) * 32 : 0) + chb) * HW
                             + row) * HW + icol;
#pragma unroll
      for (int j = 0; j < 16; ++j) v[j] = 0.0f;
      if (doL) {
#pragma unroll
        for (int j = 0; j < 16; ++j) v[j] = sp[j * PLANE];
      }

      // (b) compute this row's 3 taps from current buffer (covers load latency)
#pragma unroll
      for (int dx = 0; dx < 3; ++dx) {
        const int tap = sub * 3 + dx;
        const unsigned short* wp = Wb + tap * (O_CH * I_CH)
                                 + (wv * 32 + ln) * I_CH + k * 32 + lk4 * 8;
        short8 a0 = *reinterpret_cast<const short8*>(wp);
        short8 a1 = *reinterpret_cast<const short8*>(wp + 16 * I_CH);
        const int cc = dx + ln;
        const int rslot = lk4 ^ (cc & 3) ^ (((cc >> 2) & 1) << 1);
        const char* bp = rbuf + (sub * NCOL + cc) * 64 + rslot * 16;
#pragma unroll
        for (int nf = 0; nf < 7; ++nf) {
          short8 bb = *reinterpret_cast<const short8*>(bp + nf * 1024);
          acc[0][nf] = __builtin_amdgcn_mfma_f32_16x16x32_bf16(a0, bb, acc[0][nf], 0, 0, 0);
          acc[1][nf] = __builtin_amdgcn_mfma_f32_16x16x32_bf16(a1, bb, acc[1][nf], 0, 0, 0);
        }
      }

      // (c) pack + LDS-write the staged row into the other buffer
      if ((k < 3) && cok) {
        const int base = (sub * NCOL + c) * 64;
#pragma unroll
        for (int q = 0; q < 2; ++q) {
          union { ushort8_t s; unsigned u[4]; } pk;
          pk.u[0] = pk2bf(v[q * 8 + 0], v[q * 8 + 1]);
          pk.u[1] = pk2bf(v[q * 8 + 2], v[q * 8 + 3]);
          pk.u[2] = pk2bf(v[q * 8 + 4], v[q * 8 + 5]);
          pk.u[3] = pk2bf(v[q * 8 + 6], v[q * 8 + 7]);
          const int slot = ((chb >> 3) + q) ^ wxor;
          *reinterpret_cast<ushort8_t*>(wbuf + base + slot * 16) = pk.s;
        }
      }
    }
    if (k < 3) __syncthreads();
  }

  // ---- epilogue (verbatim R0): C/D map col=lane&15, row=(lane>>4)*4+j ----
  const int obase = wv * 32 + lk4 * 4;
  float* outp = Out + (size_t)b * O_CH * PLANE + (size_t)y * HW;
#pragma unroll
  for (int mr = 0; mr < 2; ++mr) {
#pragma unroll
    for (int j = 0; j < 4; ++j) {
      const int o = obase + mr * 16 + j;
      float* po = outp + (size_t)o * PLANE;
#pragma unroll
      for (int nf = 0; nf < 7; ++nf) {
        po[nf * 16 + ln] = acc[mr][nf][j];
      }
    }
  }
}

extern "C" void kernel_launch(void* const* d_in, const int* in_sizes, int n_in,
                              void* d_out, int out_size, void* d_ws, size_t ws_size,
                              hipStream_t stream) {
  const float* x      = (const float*)d_in[0];
  const float* core   = (const float*)d_in[1];
  const float* periph = (const float*)d_in[2];
  const float* thr    = (const float*)d_in[3];
  const float* scale  = (const float*)d_in[4];
  unsigned short* Wb  = (unsigned short*)d_ws;   // 9*128*128*2 = 294,912 B

  wsynth_kernel<<<(O_CH * I_CH + 255) / 256, 256, 0, stream>>>(core, periph, thr, scale, Wb);

  const int grid = 32 * HW;   // one WG per (batch, output row) = 3584
  conv_kernel<<<grid, 256, 0, stream>>>(x, Wb, (float*)d_out);
}

// Round 6
// 206.988 us; speedup vs baseline: 2.1112x; 1.0515x over previous
//
#include <hip/hip_runtime.h>

typedef short short8 __attribute__((ext_vector_type(8)));
typedef float f32x4 __attribute__((ext_vector_type(4)));
typedef unsigned short ushort8_t __attribute__((ext_vector_type(8)));

#define O_CH 128
#define I_CH 128
#define HW 112
#define PLANE (HW * HW)        // 12544
#define NCOL 114               // 112 cols + 2 halo
#define BUFB (3 * NCOL * 64)   // bytes per LDS buffer: 3 rows * 114 cols * 32ch * 2B

__device__ __forceinline__ unsigned short f2bf(float f) {
  union { float f; unsigned u; } v; v.f = f;
  unsigned r = v.u + 0x7FFFu + ((v.u >> 16) & 1u);   // RNE (weights only)
  return (unsigned short)(r >> 16);
}

// one-instruction truncate-pack: [lo,hi] floats -> packed bf16 pair
__device__ __forceinline__ unsigned pktrunc(float lo, float hi) {
  union { float f; unsigned u; } a, b; a.f = lo; b.f = hi;
  return __builtin_amdgcn_perm(b.u, a.u, 0x07060302u);
}

__global__ void wsynth_kernel(const float* __restrict__ core,
                              const float* __restrict__ periph,
                              const float* __restrict__ thr,
                              const float* __restrict__ scale,
                              unsigned short* __restrict__ Wb) {
  int idx = blockIdx.x * blockDim.x + threadIdx.x;   // o*128 + i
  if (idx >= O_CH * I_CH) return;
  int o = idx >> 7;
  float c = core[idx];
  float s = scale[0];
  float g = 1.0f / (1.0f + __expf(-s * (fabsf(c) - thr[o])));
#pragma unroll
  for (int tap = 0; tap < 9; ++tap) {
    float p  = (tap == 4) ? 1.0f : periph[tap < 4 ? tap : tap - 1];
    float gg = (tap == 4) ? 1.0f : g;
    Wb[tap * (O_CH * I_CH) + idx] = f2bf(c * p * gg);   // layout [tap][o][i]
  }
}

__global__ __launch_bounds__(256, 3)
void conv_kernel(const float* __restrict__ X,
                 const unsigned short* __restrict__ Wb,
                 float* __restrict__ Out) {
  // 2 buffers x [row 0..2][col 0..113][32 ch] bf16; col-row = 64 B = 4 slots of 16 B,
  // slot swizzled: slot' = kslice ^ (c&3) ^ (((c>>2)&1)<<1)
  __shared__ unsigned short Xs[2 * 3 * NCOL * 32];   // 43,776 B -> 3 WGs/CU
  char* lds = (char*)Xs;

  // XCD-chunked swizzle: 3584 = 8 XCDs x 448 contiguous logical ids
  // (R4 identity FETCH=599MB vs R3 xcd=393MB -> swizzle helps L2 row reuse)
  const int bid = blockIdx.x;
  const int L = (bid & 7) * 448 + (bid >> 3);
  const int b = L / HW;
  const int y = L - b * HW;

  const int t   = threadIdx.x;
  const int wv  = t >> 6;              // wave 0..3 -> o quarter
  const int l   = t & 63;
  const int ln  = l & 15;              // MFMA frag lane
  const int lk4 = l >> 4;              // k-slice 0..3

  // staging coords
  const int c    = t & 127;            // staged col (input col + 1)
  const int chb  = (t >> 7) * 16;      // local channel base: 0 or 16
  const int icol = c - 1;
  const bool cok = (c < NCOL);
  const int wxor = (c & 3) ^ (((c >> 2) & 1) << 1);

  f32x4 acc[2][7];
#pragma unroll
  for (int mr = 0; mr < 2; ++mr)
#pragma unroll
    for (int nf = 0; nf < 7; ++nf)
      acc[mr][nf] = (f32x4)0.0f;

#define LOAD16(V, KCH, SUB)                                                     \
  {                                                                             \
    const int row_ = y + (SUB)-1;                                               \
    const bool ok_ = (row_ >= 0) && (row_ < HW) && (icol >= 0) && (icol < HW);  \
    const float* sp_ = X + ((size_t)(b * I_CH + (KCH) + chb) * HW + row_) * HW  \
                       + icol;                                                  \
    _Pragma("unroll") for (int j = 0; j < 16; ++j) V[j] = 0.0f;                 \
    if (ok_) {                                                                  \
      _Pragma("unroll") for (int j = 0; j < 16; ++j) V[j] = sp_[j * PLANE];     \
    }                                                                           \
  }

#define WRITE16(V, SUB, WB)                                                     \
  if (cok) {                                                                    \
    const int base_ = ((SUB)*NCOL + c) * 64;                                    \
    _Pragma("unroll") for (int q = 0; q < 2; ++q) {                             \
      union { ushort8_t s; unsigned u[4]; } pk_;                                \
      pk_.u[0] = pktrunc(V[q * 8 + 0], V[q * 8 + 1]);                           \
      pk_.u[1] = pktrunc(V[q * 8 + 2], V[q * 8 + 3]);                           \
      pk_.u[2] = pktrunc(V[q * 8 + 4], V[q * 8 + 5]);                           \
      pk_.u[3] = pktrunc(V[q * 8 + 6], V[q * 8 + 7]);                           \
      const int slot_ = ((chb >> 3) + q) ^ wxor;                                \
      *reinterpret_cast<ushort8_t*>((WB) + base_ + slot_ * 16) = pk_.s;         \
    }                                                                           \
  }

#define COMPUTE_SUB(SUB, RB, K)                                                 \
  _Pragma("unroll") for (int dx = 0; dx < 3; ++dx) {                            \
    const int tap_ = (SUB)*3 + dx;                                              \
    const unsigned short* wp_ = Wb + tap_ * (O_CH * I_CH)                       \
                              + (wv * 32 + ln) * I_CH + (K)*32 + lk4 * 8;       \
    short8 a0_ = *reinterpret_cast<const short8*>(wp_);                         \
    short8 a1_ = *reinterpret_cast<const short8*>(wp_ + 16 * I_CH);             \
    const int cc_ = dx + ln;                                                    \
    const int rslot_ = lk4 ^ (cc_ & 3) ^ (((cc_ >> 2) & 1) << 1);               \
    const char* bp_ = (RB) + ((SUB)*NCOL + cc_) * 64 + rslot_ * 16;             \
    _Pragma("unroll") for (int nf = 0; nf < 7; ++nf) {                          \
      short8 bb_ = *reinterpret_cast<const short8*>(bp_ + nf * 1024);           \
      acc[0][nf] = __builtin_amdgcn_mfma_f32_16x16x32_bf16(a0_, bb_, acc[0][nf], 0, 0, 0); \
      acc[1][nf] = __builtin_amdgcn_mfma_f32_16x16x32_bf16(a1_, bb_, acc[1][nf], 0, 0, 0); \
    }                                                                           \
  }

  // ---- prologue: stage chunk 0 (channels 0..31) into buffer 0 ----
  {
    float P0[16], P1[16], P2[16];
    LOAD16(P0, 0, 0)
    LOAD16(P1, 0, 1)
    LOAD16(P2, 0, 2)
    WRITE16(P0, 0, lds)
    WRITE16(P1, 1, lds)
    WRITE16(P2, 2, lds)
  }
  __syncthreads();

  // ---- main loop: 4 chunks of 32 channels, double-buffered, lag-1 writes ----
#pragma unroll
  for (int k = 0; k < 4; ++k) {
    char* rbuf = lds + (k & 1) * BUFB;
    char* wbuf = lds + ((k & 1) ^ 1) * BUFB;
    float LA[16], LB[16];

    // sub 0: issue loads for (k+1, sub0); compute sub0
    if (k < 3) LOAD16(LA, (k + 1) * 32, 0)
    COMPUTE_SUB(0, rbuf, k)

    // sub 1: issue loads for (k+1, sub1); compute sub1; write sub0 (lag-1)
    if (k < 3) LOAD16(LB, (k + 1) * 32, 1)
    COMPUTE_SUB(1, rbuf, k)
    if (k < 3) WRITE16(LA, 0, wbuf)

    // sub 2: issue loads for (k+1, sub2); compute sub2; write sub1, sub2
    if (k < 3) LOAD16(LA, (k + 1) * 32, 2)
    COMPUTE_SUB(2, rbuf, k)
    if (k < 3) {
      WRITE16(LB, 1, wbuf)
      WRITE16(LA, 2, wbuf)
      __syncthreads();
    }
  }

  // ---- epilogue: C/D map col=lane&15, row=(lane>>4)*4+j ----
  const int obase = wv * 32 + lk4 * 4;
  float* outp = Out + (size_t)b * O_CH * PLANE + (size_t)y * HW;
#pragma unroll
  for (int mr = 0; mr < 2; ++mr) {
#pragma unroll
    for (int j = 0; j < 4; ++j) {
      const int o = obase + mr * 16 + j;
      float* po = outp + (size_t)o * PLANE;
#pragma unroll
      for (int nf = 0; nf < 7; ++nf) {
        po[nf * 16 + ln] = acc[mr][nf][j];
      }
    }
  }
}

extern "C" void kernel_launch(void* const* d_in, const int* in_sizes, int n_in,
                              void* d_out, int out_size, void* d_ws, size_t ws_size,
                              hipStream_t stream) {
  const float* x      = (const float*)d_in[0];
  const float* core   = (const float*)d_in[1];
  const float* periph = (const float*)d_in[2];
  const float* thr    = (const float*)d_in[3];
  const float* scale  = (const float*)d_in[4];
  unsigned short* Wb  = (unsigned short*)d_ws;   // 9*128*128*2 = 294,912 B

  wsynth_kernel<<<(O_CH * I_CH + 255) / 256, 256, 0, stream>>>(core, periph, thr, scale, Wb);

  const int grid = 32 * HW;   // one WG per (batch, output row) = 3584
  conv_kernel<<<grid, 256, 0, stream>>>(x, Wb, (float*)d_out);
}